// Round 5
// baseline (198.632 us; speedup 1.0000x reference)
//
#include <hip/hip_runtime.h>
#include <hip/hip_bf16.h>
#include <stdint.h>

// y[c,k] = sum_{a,b} E1[k,a] * Xc[c,a,b] * E2[k,b],  Xc = C*x, E = exp(i*angle*g)
// GEMM: tmp[a, 2k+comp] = A'[a,:] @ B'[:, 2k+comp]
//   A' = [Re(Xc) | Im(Xc)]  (256 x 512 per c)
//   B'[b,2k]=Er, B'[256+b,2k]=-Ei, B'[b,2k+1]=Ei, B'[256+b,2k+1]=Er
// Epilogue: y[c,k] = sum_a E1[k,a] (*) tmp[a,k]  (complex), * w[k%512]
//
// R5: BARRIER-FREE K-loop. Both A and B are packed in MFMA-fragment-native
// order (frag[grp][kc][lane%16][j]) so every wave's fragment load is one
// contiguous coalesced 1 KB global load, A from L2 (c pinned per XCD), B
// multicast x4 via L2. No LDS / no __syncthreads in the K-loop -> no
// vmcnt(0) barrier drain (the R2/R4 105us plateau was latency exposed at
// the per-iter barrier; true MFMA pipe busy was <10%). 16 fully-unrolled
// phases with 2-deep register ping-pong prefetch give the compiler a
// fine-grained vmcnt(N) pipeline (AITER-style). E1 is computed in the
// epilogue by sincos (E1tab removed entirely).

#define NKTOT 17408
#define NBLK_K 544   // 17408 / 32 k's per block

typedef short bf16x8 __attribute__((ext_vector_type(8)));
typedef float f32x4 __attribute__((ext_vector_type(4)));

__device__ __forceinline__ unsigned short f2bf(float f) {
  unsigned int u = __builtin_bit_cast(unsigned int, f);
  u += 0x7FFFu + ((u >> 16) & 1u);
  return (unsigned short)(u >> 16);
}

// Fused packing: blocks [0, NKTOT) write E2 -> Bfrag (fragment-native),
// blocks [NKTOT, NKTOT+2048) pack A' into fragment-native layout.
__global__ __launch_bounds__(256) void pack_all(
    const float* __restrict__ input_r, const float* __restrict__ C_r,
    const float* __restrict__ angle,
    unsigned short* __restrict__ Afrag, unsigned short* __restrict__ Bfrag)
{
  int bk = blockIdx.x;
  if (bk < NKTOT) {
    int k = bk;
    int b = threadIdx.x;          // kdim row within Re half; Im half at 256+b
    float t = angle[k * 2 + 1];
    float g = (float)(b - 128);
    float sn, cs;
    __sincosf(t * g, &sn, &cs);
    int n0 = 2 * k;
    // frag addr = colgrp*8192 + kc*128 + (n%16)*8 + (kd%8)
    size_t cg = (size_t)(n0 >> 4) * 8192;
    int llo0 = n0 & 15;
    int kcR = b >> 3, kcI = 32 + kcR, j = b & 7;
    Bfrag[cg + (size_t)kcR * 128 + llo0 * 8 + j]       = f2bf(cs);   // col 2k,   kd=b
    Bfrag[cg + (size_t)kcI * 128 + llo0 * 8 + j]       = f2bf(-sn);  // col 2k,   kd=256+b
    Bfrag[cg + (size_t)kcR * 128 + (llo0 + 1) * 8 + j] = f2bf(sn);   // col 2k+1, kd=b
    Bfrag[cg + (size_t)kcI * 128 + (llo0 + 1) * 8 + j] = f2bf(cs);   // col 2k+1, kd=256+b
  } else {
    int tid = (bk - NKTOT) * 256 + threadIdx.x;
    int b = tid & 255;
    int a = (tid >> 8) & 255;
    int c = tid >> 16;
    float xr = input_r[(a * 256 + b) * 2 + 0];
    float xi = input_r[(a * 256 + b) * 2 + 1];
    size_t ci0 = ((size_t)(c * 256 + a) * 256 + b) * 2;
    float cr = C_r[ci0 + 0];
    float ci = C_r[ci0 + 1];
    float re = cr * xr - ci * xi;
    float im = cr * xi + ci * xr;
    // Afrag[((c*16+rg)*64+kc)*128 + (a%16)*8 + (kd%8)]; Re at kd=b, Im at kd=256+b
    size_t base = (size_t)(c * 16 + (a >> 4)) * 8192 + (size_t)(a & 15) * 8 + (b & 7);
    Afrag[base + (size_t)(b >> 3) * 128]        = f2bf(re);
    Afrag[base + (size_t)(32 + (b >> 3)) * 128] = f2bf(im);
  }
}

__global__ __launch_bounds__(256, 3) void gemm_fused(
    const unsigned short* __restrict__ Afrag,
    const unsigned short* __restrict__ Bfrag,
    const float* __restrict__ angle,
    const float* __restrict__ wvec,
    float* __restrict__ out)
{
  __shared__ float wavecol[4][64];

  // c = bx&7 pins channel c to one XCD -> its 2 MB A-slab stays L2-hot.
  const int bx = blockIdx.x;
  const int c = bx & 7;
  const int kt0 = (bx >> 3) * 32;  // 32 k's (64 GEMM cols) per block
  const int tid = threadIdx.x;
  const int w = tid >> 6;
  const int l = tid & 63;
  const int lhi = l >> 4;
  const int llo = l & 15;

  // wave w owns rows w*64 .. w*64+63 (rg = w*4+fi); block owns cols
  // colgrp0 = (bx>>3)*4 .. +3. Fragment at phase kgi: base + f*8192 + kgi*512.
  const unsigned short* Aw =
      Afrag + (size_t)(c * 16 + w * 4) * 8192 + lhi * 128 + llo * 8;
  const unsigned short* Bw =
      Bfrag + (size_t)((bx >> 3) * 4) * 8192 + lhi * 128 + llo * 8;

  f32x4 acc[4][4];
#pragma unroll
  for (int i = 0; i < 4; ++i)
#pragma unroll
    for (int j = 0; j < 4; ++j) {
      f32x4 z = {0.f, 0.f, 0.f, 0.f};
      acc[i][j] = z;
    }

  bf16x8 af[2][4], bf[2][4];
#pragma unroll
  for (int p = 0; p < 2; ++p)
#pragma unroll
    for (int f = 0; f < 4; ++f) {
      af[p][f] = *(const bf16x8*)(Aw + f * 8192 + p * 512);
      bf[p][f] = *(const bf16x8*)(Bw + f * 8192 + p * 512);
    }

#pragma unroll
  for (int kgi = 0; kgi < 16; ++kgi) {
    const int cur = kgi & 1;
#pragma unroll
    for (int fi = 0; fi < 4; ++fi)
#pragma unroll
      for (int fj = 0; fj < 4; ++fj)
        acc[fi][fj] = __builtin_amdgcn_mfma_f32_16x16x32_bf16(
            af[cur][fi], bf[cur][fj], acc[fi][fj], 0, 0, 0);
    if (kgi < 14) {
      const int nk = kgi + 2;
#pragma unroll
      for (int f = 0; f < 4; ++f) {
        af[cur][f] = *(const bf16x8*)(Aw + f * 8192 + nk * 512);
        bf[cur][f] = *(const bf16x8*)(Bw + f * 8192 + nk * 512);
      }
    }
  }

  // Epilogue: y[c,k] = sum_a E1[k,a] (*) tmp[a,k]; E1 computed in-register.
  // col = fj*16 + llo in [0,64); even col = Re, odd = Im of k = kt0 + col/2
#pragma unroll
  for (int fj = 0; fj < 4; ++fj) {
    const int col = fj * 16 + llo;
    const int k = kt0 + (col >> 1);
    const float sign = (col & 1) ? 1.f : -1.f;
    const float s_ang = angle[2 * k];
    float sum = 0.f;
#pragma unroll
    for (int fi = 0; fi < 4; ++fi) {
#pragma unroll
      for (int r = 0; r < 4; ++r) {
        const int a = w * 64 + lhi * 4 + fi * 16 + r;
        float er, ei;
        __sincosf(s_ang * (float)(a - 128), &ei, &er);
        float v = acc[fi][fj][r];        // this comp at (a, k)
        float p = __shfl_xor(v, 1, 64);  // partner comp, same (a, k)
        sum += er * v + sign * ei * p;   // even: er*tr - ei*ti; odd: er*ti + ei*tr
      }
    }
    sum += __shfl_xor(sum, 16, 64);
    sum += __shfl_xor(sum, 32, 64);
    if (lhi == 0) wavecol[w][col] = sum;
  }
  __syncthreads();
  if (tid < 64) {
    float sv = wavecol[0][tid] + wavecol[1][tid] + wavecol[2][tid] + wavecol[3][tid];
    int k = kt0 + (tid >> 1);
    out[((size_t)c * NKTOT + k) * 2 + (tid & 1)] = sv * wvec[k & 511];
  }
}

extern "C" void kernel_launch(void* const* d_in, const int* in_sizes, int n_in,
                              void* d_out, int out_size, void* d_ws, size_t ws_size,
                              hipStream_t stream) {
  const float* input_r = (const float*)d_in[0];  // (256,256,2)
  const float* C_r     = (const float*)d_in[1];  // (8,256,256,2)
  const float* wvec    = (const float*)d_in[2];  // (512,)
  const float* angle   = (const float*)d_in[3];  // (17408,2)
  float* out = (float*)d_out;                    // (8,17408,2)

  // workspace: Afrag (2MB) | Bfrag (34MB)
  unsigned short* Afrag = (unsigned short*)d_ws;
  unsigned short* Bfrag = (unsigned short*)((char*)d_ws + (size_t)2097152);

  pack_all<<<NKTOT + 2048, 256, 0, stream>>>(input_r, C_r, angle, Afrag, Bfrag);
  gemm_fused<<<8 * NBLK_K, 256, 0, stream>>>(Afrag, Bfrag, angle, wvec, out);
}

// Round 6
// 163.793 us; speedup vs baseline: 1.2127x; 1.2127x over previous
//
#include <hip/hip_runtime.h>
#include <hip/hip_bf16.h>
#include <stdint.h>

// y[c,k] = sum_{a,b} E1[k,a] * Xc[c,a,b] * E2[k,b],  Xc = C*x, E = exp(i*angle*g)
// GEMM: tmp[a, 2k+comp] = A'[a,:] @ B'[:, 2k+comp]   (A' 256x512 per c)
//   B'[b,2k]=Er, B'[256+b,2k]=-Ei, B'[b,2k+1]=Ei, B'[256+b,2k+1]=Er
// Epilogue: y[c,k] = sum_a E1[k,a] (*) tmp[a,k], * w[k%512]
//
// R6: software-pipelined K-loop, AITER-style. B flows through a 3-slot LDS
// ring staged by global_load_lds at prefetch distance 2; A-fragments load
// global->register (fragment-native layout, L2-hot) also at distance 2.
// Synchronization is raw `s_barrier` (inline asm -- NO compiler-implied
// vmcnt(0) drain, which was the R2/R4 105us plateau) plus manual
// window-counted `s_waitcnt vmcnt(N)`: every iter issues exactly 6 vmem ops
// per wave, so vmcnt(12) retires precisely the chunk issued 2 iters ago.
// Tile 256x128 (acc 4x8 = 128 AGPR), 2 blocks/CU; MFMA/phase (155 cyc)
// exceeds ds_read/phase (96 cyc) -> compute-bound when latency is hidden.

#define NKTOT 17408
#define NTILE 272   // 17408 / 64 k's per block

typedef short bf16x8 __attribute__((ext_vector_type(8)));
typedef float f32x4 __attribute__((ext_vector_type(4)));

#define WAITV(N) asm volatile("s_waitcnt vmcnt(" #N ")" ::: "memory")
#define BARRIER_RAW asm volatile("s_barrier" ::: "memory")

__device__ __forceinline__ unsigned short f2bf(float f) {
  unsigned int u = __builtin_bit_cast(unsigned int, f);
  u += 0x7FFFu + ((u >> 16) & 1u);
  return (unsigned short)(u >> 16);
}
__device__ __forceinline__ float bf2f(unsigned int lo16) {
  return __builtin_bit_cast(float, lo16 << 16);
}
__device__ __forceinline__ unsigned int pkbf(float x, float y) {
  return (unsigned int)f2bf(x) | ((unsigned int)f2bf(y) << 16);
}

__device__ __forceinline__ void async_copy16(void* lds, const void* g) {
  __builtin_amdgcn_global_load_lds(
      (const __attribute__((address_space(1))) unsigned int*)g,
      (__attribute__((address_space(3))) unsigned int*)lds, 16, 0, 0);
}

// Gather-style packing (every thread computes the 16B it stores; all stores
// coalesced). Segments by blockIdx:
//   [0, 8704):      Bfrag  (2.23M thr x 8 bf16)
//   [8704, 17408):  E1tab  (2.23M thr x uint2)
//   [17408, 17920): Afrag  (131k thr x 8 bf16)
__global__ __launch_bounds__(256) void pack_all(
    const float* __restrict__ input_r, const float* __restrict__ C_r,
    const float* __restrict__ angle,
    unsigned short* __restrict__ Afrag, unsigned short* __restrict__ Bfrag,
    unsigned int* __restrict__ E1tab)
{
  int bk = blockIdx.x;
  if (bk < 8704) {
    int gid = bk * 256 + threadIdx.x;          // (cg, kc, llo)
    int llo = gid & 15, kc = (gid >> 4) & 63, cg = gid >> 10;
    int n = cg * 16 + llo;
    int k = n >> 1, odd = n & 1, half = kc >> 5, b0 = (kc & 31) * 8;
    float t = angle[2 * k + 1];
    float f[8];
#pragma unroll
    for (int j = 0; j < 8; ++j) {
      float g = (float)(b0 + j - 128);
      float sn, cs;
      __sincosf(t * g, &sn, &cs);
      f[j] = odd ? (half ? cs : sn) : (half ? -sn : cs);
    }
    uint4 o;
    o.x = pkbf(f[0], f[1]); o.y = pkbf(f[2], f[3]);
    o.z = pkbf(f[4], f[5]); o.w = pkbf(f[6], f[7]);
    *(uint4*)(Bfrag + (size_t)gid * 8) = o;
  } else if (bk < 17408) {
    int gid = (bk - 8704) * 256 + threadIdx.x;
    int b0 = (gid & 127) * 2, k = gid >> 7;
    float s = angle[2 * k];
    float g0 = (float)(b0 - 128);
    float s0, c0, s1, c1;
    __sincosf(s * g0, &s0, &c0);
    __sincosf(s * (g0 + 1.0f), &s1, &c1);
    uint2 e;
    e.x = pkbf(c0, s0);
    e.y = pkbf(c1, s1);
    *(uint2*)(E1tab + (size_t)k * 256 + b0) = e;
  } else {
    int gid = (bk - 17408) * 256 + threadIdx.x;  // (c, rg, kc, llo)
    int llo = gid & 15, kc = (gid >> 4) & 63, rg = (gid >> 10) & 15, c = gid >> 14;
    int a = rg * 16 + llo;
    int imh = kc >> 5, b0 = (kc & 31) * 8;
    float f[8];
#pragma unroll
    for (int j2 = 0; j2 < 4; ++j2) {
      float4 xin = *(const float4*)(input_r + ((size_t)a * 256 + b0 + j2 * 2) * 2);
      float4 cin = *(const float4*)(C_r + (((size_t)c * 256 + a) * 256 + b0 + j2 * 2) * 2);
      float re0 = cin.x * xin.x - cin.y * xin.y;
      float im0 = cin.x * xin.y + cin.y * xin.x;
      float re1 = cin.z * xin.z - cin.w * xin.w;
      float im1 = cin.z * xin.w + cin.w * xin.z;
      f[j2 * 2]     = imh ? im0 : re0;
      f[j2 * 2 + 1] = imh ? im1 : re1;
    }
    uint4 o;
    o.x = pkbf(f[0], f[1]); o.y = pkbf(f[2], f[3]);
    o.z = pkbf(f[4], f[5]); o.w = pkbf(f[6], f[7]);
    *(uint4*)(Afrag + (size_t)gid * 8) = o;
  }
}

__global__ __launch_bounds__(256, 2) void gemm_fused(
    const unsigned short* __restrict__ Afrag,
    const unsigned short* __restrict__ Bfrag,
    const unsigned int* __restrict__ E1tab,
    const float* __restrict__ wvec,
    float* __restrict__ out)
{
  __shared__ unsigned short Bring[3 * 4096];  // 3 ring slots x 8 KB
  __shared__ float wavecol[4][128];

  // c = bx&7 pins channel c to one XCD -> its 2 MB A-slab stays L2-hot.
  const int bx = blockIdx.x;
  const int c = bx & 7;
  const int ktile = bx >> 3;       // 0..271
  const int kt0 = ktile * 64;      // 64 k's (128 GEMM cols) per block
  const int tid = threadIdx.x;
  const int w = tid >> 6;
  const int l = tid & 63;
  const int lhi = l >> 4;
  const int llo = l & 15;

  // Fragment-native bases (1 KB per frag, lane l at byte l*16):
  const unsigned short* Abase = Afrag + (size_t)c * 131072 + l * 8;        // + rg*8192 + kg*512
  const unsigned short* Bbase = Bfrag + (size_t)(ktile * 8) * 8192 + l * 8; // + cg*8192 + kg*512

  f32x4 acc[4][8];
#pragma unroll
  for (int i = 0; i < 4; ++i)
#pragma unroll
    for (int j = 0; j < 8; ++j) {
      f32x4 z = {0.f, 0.f, 0.f, 0.f};
      acc[i][j] = z;
    }

  bf16x8 af[3][4];

  // ---- prologue: chunks 0 and 1 (each window = 2 B-lds + 4 A loads) ----
#pragma unroll
  for (int p = 0; p < 2; ++p) {
    unsigned short* slot = Bring + p * 4096;
#pragma unroll
    for (int i = 0; i < 2; ++i)
      async_copy16(slot + (w * 2 + i) * 512, Bbase + (w * 2 + i) * 8192 + p * 512);
#pragma unroll
    for (int i = 0; i < 4; ++i)
      af[p][i] = *(const bf16x8*)(Abase + (w * 4 + i) * 8192 + p * 512);
  }

  // ---- pipelined K-loop: 16 chunks of kd=32, ring D=3, distance 2 ----
#pragma unroll
  for (int kg = 0; kg < 16; ++kg) {
    if (kg <= 13) {
      const int nk = kg + 2;
      unsigned short* slot = Bring + (nk % 3) * 4096;
#pragma unroll
      for (int i = 0; i < 2; ++i)
        async_copy16(slot + (w * 2 + i) * 512, Bbase + (w * 2 + i) * 8192 + nk * 512);
#pragma unroll
      for (int i = 0; i < 4; ++i)
        af[nk % 3][i] = *(const bf16x8*)(Abase + (w * 4 + i) * 8192 + nk * 512);
    }
    // Window counting: 6 vmem/iter/wave -> vmcnt(12) retires chunk kg exactly.
    if (kg <= 13) { WAITV(12); } else if (kg == 14) { WAITV(6); } else { WAITV(0); }
    BARRIER_RAW;  // all waves' chunk-kg staging landed (raw: no vmcnt(0) drain)
    const unsigned short* slot = Bring + (kg % 3) * 4096;
    bf16x8 bfr[8];
#pragma unroll
    for (int fj = 0; fj < 8; ++fj)
      bfr[fj] = *(const bf16x8*)(slot + fj * 512 + l * 8);
#pragma unroll
    for (int fi = 0; fi < 4; ++fi)
#pragma unroll
      for (int fj = 0; fj < 8; ++fj)
        acc[fi][fj] = __builtin_amdgcn_mfma_f32_16x16x32_bf16(
            af[kg % 3][fi], bfr[fj], acc[fi][fj], 0, 0, 0);
    BARRIER_RAW;  // readers done before next iter overwrites this slot
  }

  // Epilogue: y[c,k] = sum_a E1 (*) tmp; wave w owns rows [w*64, w*64+64).
  // col = fj*16 + llo in [0,128); even col = Re, odd = Im of k = kt0 + col/2
#pragma unroll
  for (int fj = 0; fj < 8; ++fj) {
    const int col = fj * 16 + llo;
    const int k = kt0 + (col >> 1);
    const float sign = (col & 1) ? 1.f : -1.f;
    float sum = 0.f;
    const unsigned int* e1base = E1tab + (size_t)k * 256 + w * 64 + lhi * 4;
#pragma unroll
    for (int fi = 0; fi < 4; ++fi) {
      uint4 e4 = *(const uint4*)(e1base + fi * 16);
      unsigned int ev[4] = {e4.x, e4.y, e4.z, e4.w};
#pragma unroll
      for (int r = 0; r < 4; ++r) {
        float v = acc[fi][fj][r];        // this comp at (a, k)
        float p = __shfl_xor(v, 1, 64);  // partner comp, same (a, k)
        float er = bf2f(ev[r] & 0xFFFFu);
        float ei = bf2f(ev[r] >> 16);
        sum += er * v + sign * ei * p;   // even: er*tr - ei*ti; odd: er*ti + ei*tr
      }
    }
    sum += __shfl_xor(sum, 16, 64);
    sum += __shfl_xor(sum, 32, 64);
    if (lhi == 0) wavecol[w][col] = sum;
  }
  __syncthreads();
  if (tid < 128) {
    float sv = wavecol[0][tid] + wavecol[1][tid] + wavecol[2][tid] + wavecol[3][tid];
    int k = kt0 + (tid >> 1);
    out[((size_t)c * NKTOT + k) * 2 + (tid & 1)] = sv * wvec[k & 511];
  }
}

extern "C" void kernel_launch(void* const* d_in, const int* in_sizes, int n_in,
                              void* d_out, int out_size, void* d_ws, size_t ws_size,
                              hipStream_t stream) {
  const float* input_r = (const float*)d_in[0];  // (256,256,2)
  const float* C_r     = (const float*)d_in[1];  // (8,256,256,2)
  const float* wvec    = (const float*)d_in[2];  // (512,)
  const float* angle   = (const float*)d_in[3];  // (17408,2)
  float* out = (float*)d_out;                    // (8,17408,2)

  // workspace: Afrag (2MB) | Bfrag (34MB) | E1tab (17MB)
  unsigned short* Afrag = (unsigned short*)d_ws;
  unsigned short* Bfrag = (unsigned short*)((char*)d_ws + (size_t)2097152);
  unsigned int*   E1tab = (unsigned int*)((char*)d_ws + (size_t)37748736);

  pack_all<<<17920, 256, 0, stream>>>(input_r, C_r, angle, Afrag, Bfrag, E1tab);
  gemm_fused<<<8 * NTILE, 256, 0, stream>>>(Afrag, Bfrag, E1tab, wvec, out);
}